// Round 7
// baseline (229.087 us; speedup 1.0000x reference)
//
#include <hip/hip_runtime.h>
#include <hip/hip_bf16.h>

typedef unsigned short u16;
typedef __attribute__((ext_vector_type(8))) __bf16 bf8v;
typedef __attribute__((ext_vector_type(4))) float f32x4;
typedef __attribute__((ext_vector_type(4))) unsigned uint4v;

#define B_ 4
#define N_ 16384
#define M_ 16384
#define K_ 16
#define C_ 64
#define O_ 64
#define G_ 8

__device__ __forceinline__ float bf2f(u16 x){
  union { unsigned u; float f; } v; v.u = ((unsigned)x) << 16; return v.f;
}
__device__ __forceinline__ u16 f2bf(float f){
  union { float f; unsigned u; } v; v.f = f;
  unsigned u = v.u;
  return (u16)((u + 0x7FFFu + ((u >> 16) & 1u)) >> 16);
}
union pk2 { unsigned u; _Float16 h[2]; };
__device__ __forceinline__ unsigned packh(float a, float b){
  pk2 p; p.h[0] = (_Float16)a; p.h[1] = (_Float16)b; return p.u;
}

// ---------------------------------------------------------------------------
// setup_kernel (1 block): bakes all weight images into ws.
//  bw:   BwT[g][k] bf16 (16x136, Bw=[cpe_w2;-Wq]@we_w1), cinit[8]
//  wkv:  [col 0..127][k 0..71] bf16 image of [Wk|Wv]^T (k>=64 zero)
//  bias: [bk|bv] f32[128];  cpe: folded cpe_w1*s (192) + cpe_b (64) f32
// ---------------------------------------------------------------------------
__global__ __launch_bounds__(256) void setup_kernel(
    const float* __restrict__ Wq, const float* __restrict__ bq,
    const float* __restrict__ cpe_w2, const float* __restrict__ cpe_b2,
    const float* __restrict__ we_w1,
    const float* __restrict__ Wk, const float* __restrict__ bk,
    const float* __restrict__ Wv, const float* __restrict__ bv,
    const float* __restrict__ cpe_w1, const float* __restrict__ cpe_s, const float* __restrict__ cpe_b,
    u16* __restrict__ bw, float* __restrict__ cinit,
    u16* __restrict__ wkv, float* __restrict__ bias, float* __restrict__ cpe)
{
  __shared__ float sWe[512];
  int tid = threadIdx.x;
  for (int e = tid; e < 512; e += 256) sWe[e] = we_w1[e];
  __syncthreads();
  {
    int k = tid >> 1, g0 = (tid & 1)*4;
    const float* brow = (k < 64) ? (cpe_w2 + k*64) : (Wq + (k-64)*64);
    float sgn = (k < 64) ? 1.f : -1.f;
    float aw[4] = {0.f,0.f,0.f,0.f};
    for (int o = 0; o < 64; o++){
      float bo = brow[o]*sgn;
      #pragma unroll
      for (int gg=0; gg<4; gg++) aw[gg] += bo * sWe[o*8 + g0+gg];
    }
    #pragma unroll
    for (int gg=0; gg<4; gg++) bw[(g0+gg)*136 + k] = f2bf(aw[gg]);
  }
  for (int e = tid; e < 2176; e += 256){
    int r = e / 136, cc = e % 136;
    if (r >= 8 || cc >= 128) bw[e] = 0;
  }
  if (tid < 8){
    float s = 0.f;
    for (int o = 0; o < 64; o++) s += (cpe_b2[o] - bq[o]) * sWe[o*8 + tid];
    cinit[tid] = s;
  }
  for (int e = tid; e < 9216; e += 256){
    int col = e / 72, k = e - col*72;
    float v = 0.f;
    if (k < 64) v = (col < 64) ? Wk[k*64 + col] : Wv[k*64 + (col-64)];
    wkv[e] = f2bf(v);
  }
  if (tid < 128) bias[tid] = (tid < 64) ? bk[tid] : bv[tid-64];
  if (tid < 64){
    float sc = cpe_s[tid];
    cpe[tid]      = cpe_w1[tid]*sc;
    cpe[64+tid]   = cpe_w1[64+tid]*sc;
    cpe[128+tid]  = cpe_w1[128+tid]*sc;
    cpe[192+tid]  = cpe_b[tid];
  }
}

// ---------------------------------------------------------------------------
// pre_kernel: blocks [0,256) KV, [256,512) QC.  256 points/block, 4 sub-tiles.
// Weight LDS images copied wide from ws (baked by setup_kernel).
// MFMA 16x16x32 bf16: A[m=l&15][k=(l>>4)*8+j], B[k][n=l&15],
//                     C/D row=(l>>4)*4+r, col=l&15.
// ---------------------------------------------------------------------------
__global__ __launch_bounds__(256) void pre_kernel(
    const float* __restrict__ center_pos, const float* __restrict__ center_fea,
    const float* __restrict__ fea,
    const u16* __restrict__ bw, const float* __restrict__ cinit,
    const u16* __restrict__ wkv, const float* __restrict__ bias, const float* __restrict__ cpe,
    u16* __restrict__ xk, u16* __restrict__ xv, float* __restrict__ qw)
{
  __shared__ u16 sWT[128*72];     // KV: [col][k]; QC: bw image at base
  __shared__ u16 sA[64*72];       // staged A tile [n][k]
  __shared__ u16 sOut[64*136];    // KV epilogue; QC: sQ f32[512] at base
  __shared__ float sMisc[256];
  int tid = threadIdx.x;
  int l = tid & 63, w = tid >> 6, c = l & 15, q = l >> 4;
  int blk = blockIdx.x;

  if (blk < 256){
    // ================ KV ================
    int P0 = blk * 256; int b = P0 >> 14; int n00 = P0 & (N_-1);
    const float* fb = fea + (long)b*C_*N_;
    for (int e = tid; e < 1152; e += 256)
      ((uint4v*)sWT)[e] = ((const uint4v*)wkv)[e];
    if (tid < 128) sMisc[tid] = bias[tid];

    #pragma unroll 1
    for (int s = 0; s < 4; s++){
      int n0 = n00 + s*64;
      #pragma unroll
      for (int pp = 0; pp < 4; pp++){
        int k = pp*16 + (tid >> 4);
        int nf = (tid & 15)*4;
        f32x4 v = *(const f32x4*)&fb[(long)k*N_ + n0 + nf];
        sA[(nf+0)*72+k] = f2bf(v[0]); sA[(nf+1)*72+k] = f2bf(v[1]);
        sA[(nf+2)*72+k] = f2bf(v[2]); sA[(nf+3)*72+k] = f2bf(v[3]);
      }
      __syncthreads();

      bf8v af0 = *(const bf8v*)&sA[(w*16+c)*72 + q*8];
      bf8v af1 = *(const bf8v*)&sA[(w*16+c)*72 + 32 + q*8];
      f32x4 acc[8];
      #pragma unroll
      for (int t = 0; t < 8; t++){
        float bb = sMisc[16*t + c];
        f32x4 a_ = {bb, bb, bb, bb};
        bf8v b0 = *(const bf8v*)&sWT[(16*t + c)*72 + q*8];
        bf8v b1 = *(const bf8v*)&sWT[(16*t + c)*72 + 32 + q*8];
        a_ = __builtin_amdgcn_mfma_f32_16x16x32_bf16(af0, b0, a_, 0,0,0);
        a_ = __builtin_amdgcn_mfma_f32_16x16x32_bf16(af1, b1, a_, 0,0,0);
        acc[t] = a_;
      }
      #pragma unroll
      for (int t = 0; t < 8; t++)
        #pragma unroll
        for (int r = 0; r < 4; r++)
          sOut[(w*16 + q*4 + r)*136 + 16*t + c] = f2bf(acc[t][r]);
      __syncthreads();

      #pragma unroll
      for (int rep = 0; rep < 4; rep++){
        int chunk = rep*256 + tid;
        int pt = chunk >> 4, c8i = chunk & 15;
        uint4v val = *(const uint4v*)&sOut[pt*136 + c8i*8];
        int col8 = c8i*8;
        long row = (long)P0 + s*64 + pt;
        if (col8 < 64) *(uint4v*)(xk + row*64 + col8)      = val;
        else           *(uint4v*)(xv + row*64 + (col8-64)) = val;
      }
      __syncthreads();
    }
  } else {
    // ================ QC ================
    int P0 = (blk - 256) * 256; int b = P0 >> 14; int m00 = P0 & (M_-1);
    const float* cfb = center_fea + (long)b*C_*M_;
    float* sQ = (float*)sOut;
    for (int e = tid; e < 272; e += 256)
      ((uint4v*)sWT)[e] = ((const uint4v*)bw)[e];
    if (tid < 256) sMisc[tid] = cpe[tid];

    #pragma unroll 1
    for (int s = 0; s < 4; s++){
      int m0 = m00 + s*64;
      #pragma unroll
      for (int pp = 0; pp < 4; pp++){
        int k = pp*16 + (tid >> 4);
        int nf = (tid & 15)*4;
        f32x4 v = *(const f32x4*)&cfb[(long)k*M_ + m0 + nf];
        sA[(nf+0)*72+k] = f2bf(v[0]); sA[(nf+1)*72+k] = f2bf(v[1]);
        sA[(nf+2)*72+k] = f2bf(v[2]); sA[(nf+3)*72+k] = f2bf(v[3]);
      }
      long c3 = (long)(P0 + s*64 + w*16 + c)*3;
      float cp0 = center_pos[c3], cp1 = center_pos[c3+1], cp2 = center_pos[c3+2];
      __syncthreads();

      bf8v ah[2];
      #pragma unroll
      for (int ks = 0; ks < 2; ks++){
        union { bf8v v; u16 sv[8]; } ua;
        #pragma unroll
        for (int j = 0; j < 8; j++){
          int h = ks*32 + q*8 + j;
          float hv = cp0*sMisc[h] + cp1*sMisc[64+h] + cp2*sMisc[128+h] + sMisc[192+h];
          ua.sv[j] = f2bf(fmaxf(hv, 0.f));
        }
        ah[ks] = ua.v;
      }
      bf8v acf0 = *(const bf8v*)&sA[(w*16+c)*72 + q*8];
      bf8v acf1 = *(const bf8v*)&sA[(w*16+c)*72 + 32 + q*8];

      float ci = (c < 8) ? cinit[c] : 0.f;
      f32x4 aq = {ci, ci, ci, ci};
      {
        bf8v b0 = *(const bf8v*)&sWT[c*136 + q*8];
        bf8v b1 = *(const bf8v*)&sWT[c*136 + 32 + q*8];
        bf8v b2 = *(const bf8v*)&sWT[c*136 + 64 + q*8];
        bf8v b3 = *(const bf8v*)&sWT[c*136 + 96 + q*8];
        aq = __builtin_amdgcn_mfma_f32_16x16x32_bf16(ah[0], b0, aq, 0,0,0);
        aq = __builtin_amdgcn_mfma_f32_16x16x32_bf16(ah[1], b1, aq, 0,0,0);
        aq = __builtin_amdgcn_mfma_f32_16x16x32_bf16(acf0,  b2, aq, 0,0,0);
        aq = __builtin_amdgcn_mfma_f32_16x16x32_bf16(acf1,  b3, aq, 0,0,0);
      }
      __syncthreads();
      if (c < 8){
        #pragma unroll
        for (int r = 0; r < 4; r++) sQ[(w*16 + q*4 + r)*8 + c] = aq[r];
      }
      __syncthreads();
      for (int e = tid; e < 512; e += 256)
        qw[(long)(P0 + s*64)*8 + e] = sQ[e];
      __syncthreads();
    }
  }
}

// ---------------------------------------------------------------------------
// attn_kernel: 1 point/wave/iter, 8 iters. ds-lean design:
//  - wl logits via 3rd MFMA (hidden LDS round trip)
//  - V contraction per-lane-output (f32 LDS tile + f16 weight rows)
//  - P contraction in C-layout with bpermute weights + cross-quad reduce
// ---------------------------------------------------------------------------
__global__ __launch_bounds__(256) void attn_kernel(
    const float* __restrict__ center_pos, const float* __restrict__ pos,
    const int* __restrict__ idx,
    const float* __restrict__ pe_w1, const float* __restrict__ pe_s, const float* __restrict__ pe_b,
    const float* __restrict__ pe_w2, const float* __restrict__ pe_b2,
    const float* __restrict__ we_w1, const float* __restrict__ we_s, const float* __restrict__ we_b,
    const float* __restrict__ we_w2, const float* __restrict__ we_b2,
    const u16* __restrict__ xk, const u16* __restrict__ xv, const float* __restrict__ qw,
    float* __restrict__ out)
{
  int tid = threadIdx.x;
  __shared__ float s_w1f[192], s_pb[64], s_pb2[64], s_ww2[64];
  __shared__ float s_ws8[8], s_wb8[8], s_wb28[8];
  __shared__ f32x4 s_dyn4[1232];   // 19712 B union: stage(11520) / per-wave tiles(4*4928)
  __shared__ float s_tile[32*66];

  char* dynb = (char*)s_dyn4;

  if (tid < 64){
    float sc = pe_s[tid];
    s_w1f[tid]     = pe_w1[tid]*sc;
    s_w1f[64+tid]  = pe_w1[64+tid]*sc;
    s_w1f[128+tid] = pe_w1[128+tid]*sc;
    s_pb[tid]  = pe_b[tid];
    s_pb2[tid] = pe_b2[tid];
    s_ww2[tid] = we_w2[tid];
  }
  if (tid >= 64 && tid < 72){
    int g = tid-64;
    s_ws8[g]=we_s[g]; s_wb8[g]=we_b[g]; s_wb28[g]=we_b2[g];
  }
  // stage pe_w2^T [col o][k] stride 72 u16
  u16* stg = (u16*)dynb;
  #pragma unroll
  for (int pp = 0; pp < 4; pp++){
    int row = pp*16 + (tid >> 4);
    int colf = (tid & 15)*4;
    f32x4 v = *(const f32x4*)&pe_w2[row*64 + colf];
    stg[(colf+0)*72+row] = f2bf(v[0]); stg[(colf+1)*72+row] = f2bf(v[1]);
    stg[(colf+2)*72+row] = f2bf(v[2]); stg[(colf+3)*72+row] = f2bf(v[3]);
  }
  // stage we_w1^T rows 0..7, zero rows 8..15
  u16* stg2 = (u16*)(dynb + 9216);
  for (int e = tid; e < 512; e += 256){
    int k = e >> 3, cc = e & 7;
    stg2[cc*72 + k] = f2bf(we_w1[e]);
  }
  for (int e = tid; e < 576; e += 256) stg2[576 + e] = 0;
  __syncthreads();

  int w = tid >> 6, l = tid & 63, c = l & 15, q = l >> 4, c8 = c & 7, qb = l & 48;

  bf8v pw2f[4][2], ww1f[2], w2B;
  #pragma unroll
  for (int t = 0; t < 4; t++){
    pw2f[t][0] = *(const bf8v*)&stg[(t*16+c)*72 + q*8];
    pw2f[t][1] = *(const bf8v*)&stg[(t*16+c)*72 + 32 + q*8];
  }
  ww1f[0] = *(const bf8v*)&stg2[c*72 + q*8];
  ww1f[1] = *(const bf8v*)&stg2[c*72 + 32 + q*8];
  {
    union { bf8v v; u16 s[8]; } uu;
    #pragma unroll
    for (int j = 0; j < 8; j++)
      uu.s[j] = (q == 0 && c < 8) ? f2bf(s_ww2[j*8 + c]) : (u16)0;
    w2B = uu.v;
  }
  float ws_c = s_ws8[c8], wb_c = s_wb8[c8], wb2_c = s_wb28[c8];
  float pb2l = s_pb2[l];
  __syncthreads();   // all waves done reading stage region before tile writes

  // per-wave tile pointers (union region)
  float* sv  = (float*)(dynb + w*4928);            // 16 x 68 f32 (272 B rows)
  u16*  swt  = (u16*) (dynb + w*4928 + 4352);      // 8 x 20 u16 (40 B rows), f16 pairs
  u16*  sh   = (u16*) (dynb + w*4928 + 4672);      // 16 x 8 bf16 (16 B rows)

  int pbase = blockIdx.x * 32;
  int b = pbase >> 14;
  long xkb = (long)b * N_ * 64;
  int ch = c >> 3;
  int gl = (l >> 3) & 7;

  // --- prefetch everything for i=0 ---
  int p = pbase + w*8;
  int iv = idx[(long)p*16 + c];
  float qpv = qw[(long)p*8 + c8];
  long c30 = (long)p*3;
  float cp0 = center_pos[c30], cp1 = center_pos[c30+1], cp2 = center_pos[c30+2];
  long pr30 = ((long)b*N_ + iv) * 3;
  float px = pos[pr30], py = pos[pr30+1], pz = pos[pr30+2];
  const u16* krow0 = xk + xkb + (long)iv * 64;
  bf8v ka0 = *(const bf8v*)(krow0 + q*8);
  bf8v ka1 = *(const bf8v*)(krow0 + 32 + q*8);
  const u16* vrow0 = xv + xkb + (long)iv * 64;
  uint4v va0 = *(const uint4v*)(vrow0 + q*8);
  uint4v va1 = *(const uint4v*)(vrow0 + 32 + q*8);

  #pragma unroll 1
  for (int i = 0; i < 8; i++){
    // ---- prefetch i+1 ----
    int pn = p + ((i < 7) ? 1 : 0);
    int iv_n = idx[(long)pn*16 + c];
    float qpv_n = qw[(long)pn*8 + c8];
    long c3n = (long)pn*3;
    float cpn0 = center_pos[c3n], cpn1 = center_pos[c3n+1], cpn2 = center_pos[c3n+2];
    long pr3n = ((long)b*N_ + iv_n) * 3;
    float pxn = pos[pr3n], pyn = pos[pr3n+1], pzn = pos[pr3n+2];
    const u16* krn = xk + xkb + (long)iv_n * 64;
    bf8v kan0 = *(const bf8v*)(krn + q*8);
    bf8v kan1 = *(const bf8v*)(krn + 32 + q*8);
    const u16* vrn = xv + xkb + (long)iv_n * 64;
    uint4v van0 = *(const uint4v*)(vrn + q*8);
    uint4v van1 = *(const uint4v*)(vrn + 32 + q*8);

    // ---- write V f32 tile: row k=c, cols q*8.. and 32+q*8.. ----
    {
      union { uint4v u; u16 s[8]; } A0, A1;
      A0.u = va0; A1.u = va1;
      f32x4 vf0, vf1, vf2, vf3;
      #pragma unroll
      for (int jj = 0; jj < 4; jj++){
        vf0[jj] = bf2f(A0.s[jj]);   vf1[jj] = bf2f(A0.s[4+jj]);
        vf2[jj] = bf2f(A1.s[jj]);   vf3[jj] = bf2f(A1.s[4+jj]);
      }
      f32x4* d0 = (f32x4*)&sv[c*68 + q*8];
      d0[0] = vf0; d0[1] = vf1;
      f32x4* d1 = (f32x4*)&sv[c*68 + 32 + q*8];
      d1[0] = vf2; d1[1] = vf3;
    }

    // ---- H1 fragments ----
    float np0 = px - cp0, np1 = py - cp1, np2 = pz - cp2;
    bf8v h1f[2];
    #pragma unroll
    for (int ks = 0; ks < 2; ks++){
      union { bf8v v; u16 s[8]; } hu;
      #pragma unroll
      for (int j = 0; j < 8; j++){
        int o = ks*32 + q*8 + j;
        float hv = np0*s_w1f[o] + np1*s_w1f[64+o] + np2*s_w1f[128+o] + s_pb[o];
        hu.s[j] = f2bf(fmaxf(hv, 0.f));
      }
      h1f[ks] = hu.v;
    }

    // ---- weight-MLP hidden via MFMA ----
    f32x4 h2a = {qpv, qpv, qpv, qpv};
    h2a = __builtin_amdgcn_mfma_f32_16x16x32_bf16(ka0, ww1f[0], h2a, 0,0,0);
    h2a = __builtin_amdgcn_mfma_f32_16x16x32_bf16(ka1, ww1f[1], h2a, 0,0,0);

    // hidden -> LDS (rows k, 8 bf16) ; only cols g=c<8 valid
    if (c < 8){
      #pragma unroll
      for (int r = 0; r < 4; r++)
        sh[(q*4+r)*8 + c] = f2bf(fmaxf(h2a[r]*ws_c + wb_c, 0.f));
    }
    // read hidden row k=c as A-frag (kk=g via q=0 only)
    bf8v hrow = *(const bf8v*)&sh[c*8];
    bf8v zf; { union { bf8v v; u16 s[8]; } uz;
      #pragma unroll
      for (int j=0;j<8;j++) uz.s[j]=0; zf = uz.v; }
    bf8v ahf = (q == 0) ? hrow : zf;

    // logits via MFMA: wl[r] = logit[k=q*4+r][go=c]
    f32x4 wlv = {wb2_c, wb2_c, wb2_c, wb2_c};
    wlv = __builtin_amdgcn_mfma_f32_16x16x32_bf16(ahf, w2B, wlv, 0,0,0);

    // softmax over 16 neighbors (no max-sub; logits O(1))
    float e0 = exp2f(wlv[0]*1.44269504f);
    float e1 = exp2f(wlv[1]*1.44269504f);
    float e2 = exp2f(wlv[2]*1.44269504f);
    float e3 = exp2f(wlv[3]*1.44269504f);
    float sm = e0+e1+e2+e3;
    sm += __shfl_xor(sm, 16, 64);
    sm += __shfl_xor(sm, 32, 64);
    float rn = 1.0f / sm;
    e0 *= rn; e1 *= rn; e2 *= rn; e3 *= rn;
    unsigned ep0 = packh(e0, e1), ep1 = packh(e2, e3);

    // weight rows to LDS: wT[g=c][k] f16 pairs (c<8 lanes, all quads)
    if (c < 8){
      *(unsigned*)&swt[c*20 + q*4]     = ep0;
      *(unsigned*)&swt[c*20 + q*4 + 2] = ep1;
    }

    // ---- P part: MFMA + bpermute weights + cross-quad reduce ----
    float ov[4];
    #pragma unroll
    for (int t = 0; t < 4; t++){
      f32x4 z = {0.f,0.f,0.f,0.f};
      z = __builtin_amdgcn_mfma_f32_16x16x32_bf16(h1f[0], pw2f[t][0], z, 0,0,0);
      z = __builtin_amdgcn_mfma_f32_16x16x32_bf16(h1f[1], pw2f[t][1], z, 0,0,0);
      int src = qb | (t*2 + ch);
      pk2 wA; wA.u = (unsigned)__shfl((int)ep0, src, 64);
      pk2 wB; wB.u = (unsigned)__shfl((int)ep1, src, 64);
      ov[t] = z[0]*(float)wA.h[0] + z[1]*(float)wA.h[1]
            + z[2]*(float)wB.h[0] + z[3]*(float)wB.h[1];
    }
    #pragma unroll
    for (int t = 0; t < 4; t++){
      ov[t] += __shfl_xor(ov[t], 16, 64);
      ov[t] += __shfl_xor(ov[t], 32, 64);
    }
    float ovsel = ov[0];
    ovsel = (q==1) ? ov[1] : ovsel;
    ovsel = (q==2) ? ov[2] : ovsel;
    ovsel = (q==3) ? ov[3] : ovsel;

    // ---- V part: per-lane output o=l, 16-tap dot ----
    float acc = 0.f;
    {
      const unsigned* wr = (const unsigned*)&swt[gl*20];
      #pragma unroll
      for (int k2 = 0; k2 < 8; k2++){
        pk2 wp; wp.u = wr[k2];
        acc += sv[(2*k2)*68 + l]   * (float)wp.h[0];
        acc += sv[(2*k2+1)*68 + l] * (float)wp.h[1];
      }
    }

    s_tile[(w*8+i)*66 + l] = ovsel + acc + pb2l;

    // rotate prefetched state
    p = pn; iv = iv_n; qpv = qpv_n;
    cp0 = cpn0; cp1 = cpn1; cp2 = cpn2;
    px = pxn; py = pyn; pz = pzn;
    ka0 = kan0; ka1 = kan1; va0 = van0; va1 = van1;
  }
  __syncthreads();

  // coalesced transposed store: out[b][o][m0+pt]
  int o0 = tid >> 5, pt = tid & 31;
  int m0 = pbase & (M_-1);
  long outb = ((long)b*64) * M_ + m0 + pt;
  #pragma unroll
  for (int ii = 0; ii < 8; ii++){
    int o = o0*8 + ii;
    out[outb + (long)o*M_] = s_tile[pt*66 + o];
  }
}

extern "C" void kernel_launch(void* const* d_in, const int* in_sizes, int n_in,
                              void* d_out, int out_size, void* d_ws, size_t ws_size,
                              hipStream_t stream) {
  const float* center_pos = (const float*)d_in[0];
  const float* center_fea = (const float*)d_in[1];
  const float* pos        = (const float*)d_in[2];
  const float* fea        = (const float*)d_in[3];
  const int*   idx        = (const int*)d_in[4];
  const float* Wq = (const float*)d_in[5];   const float* bq = (const float*)d_in[6];
  const float* Wk = (const float*)d_in[7];   const float* bk = (const float*)d_in[8];
  const float* Wv = (const float*)d_in[9];   const float* bv = (const float*)d_in[10];
  const float* cpe_w1 = (const float*)d_in[11]; const float* cpe_s = (const float*)d_in[12];
  const float* cpe_b  = (const float*)d_in[13]; const float* cpe_w2 = (const float*)d_in[14];
  const float* cpe_b2 = (const float*)d_in[15];
  const float* pe_w1 = (const float*)d_in[16]; const float* pe_s = (const float*)d_in[17];
  const float* pe_b  = (const float*)d_in[18]; const float* pe_w2 = (const float*)d_in[19];
  const float* pe_b2 = (const float*)d_in[20];
  const float* we_w1 = (const float*)d_in[21]; const float* we_s = (const float*)d_in[22];
  const float* we_b  = (const float*)d_in[23]; const float* we_w2 = (const float*)d_in[24];
  const float* we_b2 = (const float*)d_in[25];

  // ws: xk u16 | xv u16 | qw f32 | bw u16(2176) | cinit f32(8)
  //   | wkv u16(9216) | bias f32(128) | cpe f32(256)
  const size_t SZ = (size_t)B_*N_*64;
  u16* xk = (u16*)d_ws;
  u16* xv = xk + SZ;
  float* qwp = (float*)(xv + SZ);
  u16* bwp = (u16*)(qwp + (size_t)B_*M_*8);
  float* cinitp = (float*)(bwp + 2176);
  u16* wkvp = (u16*)(cinitp + 8);
  float* biasp = (float*)(wkvp + 9216);
  float* cpep = biasp + 128;
  float* outp = (float*)d_out;

  hipLaunchKernelGGL(setup_kernel, dim3(1), dim3(256), 0, stream,
      Wq, bq, cpe_w2, cpe_b2, we_w1, Wk, bk, Wv, bv,
      cpe_w1, cpe_s, cpe_b, bwp, cinitp, wkvp, biasp, cpep);
  hipLaunchKernelGGL(pre_kernel, dim3(512), dim3(256), 0, stream,
      center_pos, center_fea, fea, bwp, cinitp, wkvp, biasp, cpep,
      xk, xv, qwp);
  hipLaunchKernelGGL(attn_kernel, dim3(2048), dim3(256), 0, stream,
      center_pos, pos, idx, pe_w1, pe_s, pe_b, pe_w2, pe_b2,
      we_w1, we_s, we_b, we_w2, we_b2, xk, xv, qwp, outp);
}

// Round 8
// 207.704 us; speedup vs baseline: 1.1029x; 1.1029x over previous
//
#include <hip/hip_runtime.h>
#include <hip/hip_bf16.h>

typedef unsigned short u16;
typedef __attribute__((ext_vector_type(8))) __bf16 bf8v;
typedef __attribute__((ext_vector_type(8))) _Float16 f16x8;
typedef __attribute__((ext_vector_type(2))) _Float16 h2v;
typedef __attribute__((ext_vector_type(4))) float f32x4;
typedef __attribute__((ext_vector_type(4))) unsigned uint4v;

#define B_ 4
#define N_ 16384
#define M_ 16384
#define K_ 16
#define C_ 64
#define O_ 64
#define G_ 8

__device__ __forceinline__ float bf2f(u16 x){
  union { unsigned u; float f; } v; v.u = ((unsigned)x) << 16; return v.f;
}
__device__ __forceinline__ u16 f2bf(float f){
  union { float f; unsigned u; } v; v.f = f;
  unsigned u = v.u;
  return (u16)((u + 0x7FFFu + ((u >> 16) & 1u)) >> 16);
}
__device__ __forceinline__ u16 f2h(float f){
  union { _Float16 h; u16 u; } v; v.h = (_Float16)f; return v.u;
}
__device__ __forceinline__ h2v mkh2(float a, float b){
  h2v r = {(_Float16)a, (_Float16)b}; return r;
}

// ---------------------------------------------------------------------------
// pre_kernel: blocks [0,256) KV (+pos4 pack), [256,512) QC (+cp4 pack, inline
// Bw setup).  256 points/block, 4 sub-tiles of 64.
// MFMA 16x16x32 bf16: A[m=l&15][k=(l>>4)*8+j], B[k][n=l&15],
//                     C/D row=(l>>4)*4+r, col=l&15.
// ---------------------------------------------------------------------------
__global__ __launch_bounds__(256) void pre_kernel(
    const float* __restrict__ center_pos, const float* __restrict__ center_fea,
    const float* __restrict__ pos, const float* __restrict__ fea,
    const float* __restrict__ Wq, const float* __restrict__ bq,
    const float* __restrict__ Wk, const float* __restrict__ bk,
    const float* __restrict__ Wv, const float* __restrict__ bv,
    const float* __restrict__ cpe_w1, const float* __restrict__ cpe_s, const float* __restrict__ cpe_b,
    const float* __restrict__ cpe_w2, const float* __restrict__ cpe_b2,
    const float* __restrict__ we_w1,
    u16* __restrict__ xk, u16* __restrict__ xv, float* __restrict__ qw,
    float* __restrict__ pos4, float* __restrict__ cp4)
{
  __shared__ u16 sWT[128*72];     // KV: [col][k]; QC: Bw image 16x136 at base
  __shared__ u16 sA[64*72];       // staged A tile [n][k]
  __shared__ u16 sOut[64*136];    // KV epilogue; QC: sWe f32[512] then sQ f32[512]
  __shared__ float sMisc[256];
  __shared__ float sCi[8];
  int tid = threadIdx.x;
  int l = tid & 63, w = tid >> 6, c = l & 15, q = l >> 4;
  int blk = blockIdx.x;

  if (blk < 256){
    // ================ KV ================
    int P0 = blk * 256; int b = P0 >> 14; int n00 = P0 & (N_-1);
    const float* fb = fea + (long)b*C_*N_;
    for (int e = tid; e < 8192; e += 256){
      int k = e >> 7, col = e & 127;
      float v = (col < 64) ? Wk[k*64 + col] : Wv[k*64 + (col-64)];
      sWT[col*72 + k] = f2bf(v);
    }
    if (tid < 128) sMisc[tid] = (tid < 64) ? bk[tid] : bv[tid-64];
    // pack pos4 records for this block's 256 points
    {
      long pg = (long)P0 + tid;
      f32x4 r = {pos[pg*3], pos[pg*3+1], pos[pg*3+2], 0.f};
      ((f32x4*)pos4)[pg] = r;
    }

    #pragma unroll 1
    for (int s = 0; s < 4; s++){
      int n0 = n00 + s*64;
      #pragma unroll
      for (int pp = 0; pp < 4; pp++){
        int k = pp*16 + (tid >> 4);
        int nf = (tid & 15)*4;
        f32x4 v = *(const f32x4*)&fb[(long)k*N_ + n0 + nf];
        sA[(nf+0)*72+k] = f2bf(v[0]); sA[(nf+1)*72+k] = f2bf(v[1]);
        sA[(nf+2)*72+k] = f2bf(v[2]); sA[(nf+3)*72+k] = f2bf(v[3]);
      }
      __syncthreads();

      bf8v af0 = *(const bf8v*)&sA[(w*16+c)*72 + q*8];
      bf8v af1 = *(const bf8v*)&sA[(w*16+c)*72 + 32 + q*8];
      f32x4 acc[8];
      #pragma unroll
      for (int t = 0; t < 8; t++){
        float bb = sMisc[16*t + c];
        f32x4 a_ = {bb, bb, bb, bb};
        bf8v b0 = *(const bf8v*)&sWT[(16*t + c)*72 + q*8];
        bf8v b1 = *(const bf8v*)&sWT[(16*t + c)*72 + 32 + q*8];
        a_ = __builtin_amdgcn_mfma_f32_16x16x32_bf16(af0, b0, a_, 0,0,0);
        a_ = __builtin_amdgcn_mfma_f32_16x16x32_bf16(af1, b1, a_, 0,0,0);
        acc[t] = a_;
      }
      #pragma unroll
      for (int t = 0; t < 8; t++)
        #pragma unroll
        for (int r = 0; r < 4; r++)
          sOut[(w*16 + q*4 + r)*136 + 16*t + c] = f2bf(acc[t][r]);
      __syncthreads();

      #pragma unroll
      for (int rep = 0; rep < 4; rep++){
        int chunk = rep*256 + tid;
        int pt = chunk >> 4, c8i = chunk & 15;
        uint4v val = *(const uint4v*)&sOut[pt*136 + c8i*8];
        int col8 = c8i*8;
        long row = (long)P0 + s*64 + pt;
        if (col8 < 64) *(uint4v*)(xk + row*64 + col8)      = val;
        else           *(uint4v*)(xv + row*64 + (col8-64)) = val;
      }
      __syncthreads();
    }
  } else {
    // ================ QC (inline setup) ================
    int P0 = (blk - 256) * 256; int b = P0 >> 14; int m00 = P0 & (M_-1);
    const float* cfb = center_fea + (long)b*C_*M_;
    float* sWe = (float*)sOut;
    float* sQ  = (float*)sOut;
    for (int e = tid; e < 512; e += 256) sWe[e] = we_w1[e];
    if (tid < 64){
      float sc = cpe_s[tid];
      sMisc[tid]     = cpe_w1[tid]*sc;
      sMisc[64+tid]  = cpe_w1[64+tid]*sc;
      sMisc[128+tid] = cpe_w1[128+tid]*sc;
      sMisc[192+tid] = cpe_b[tid];
    }
    // pack cp4 records
    {
      long pg = (long)P0 + tid;
      f32x4 r = {center_pos[pg*3], center_pos[pg*3+1], center_pos[pg*3+2], 0.f};
      ((f32x4*)cp4)[pg] = r;
    }
    __syncthreads();
    // Bw[k][g] = sum_o [cpe_w2;-Wq][k][o]*we_w1[o][g] -> BwT[g][k] bf16
    {
      int k = tid >> 1, g0 = (tid & 1)*4;
      const float* brow = (k < 64) ? (cpe_w2 + k*64) : (Wq + (k-64)*64);
      float sgn = (k < 64) ? 1.f : -1.f;
      float aw[4] = {0.f,0.f,0.f,0.f};
      for (int o = 0; o < 64; o++){
        float bo = brow[o]*sgn;
        #pragma unroll
        for (int gg=0; gg<4; gg++) aw[gg] += bo * sWe[o*8 + g0+gg];
      }
      #pragma unroll
      for (int gg=0; gg<4; gg++) sWT[(g0+gg)*136 + k] = f2bf(aw[gg]);
    }
    for (int e = tid; e < 2176; e += 256){
      int r = e / 136, cc = e % 136;
      if (r >= 8 || cc >= 128) sWT[e] = 0;
    }
    if (tid < 8){
      float s = 0.f;
      for (int o = 0; o < 64; o++) s += (cpe_b2[o] - bq[o]) * sWe[o*8 + tid];
      sCi[tid] = s;
    }
    __syncthreads();

    #pragma unroll 1
    for (int s = 0; s < 4; s++){
      int m0 = m00 + s*64;
      #pragma unroll
      for (int pp = 0; pp < 4; pp++){
        int k = pp*16 + (tid >> 4);
        int nf = (tid & 15)*4;
        f32x4 v = *(const f32x4*)&cfb[(long)k*M_ + m0 + nf];
        sA[(nf+0)*72+k] = f2bf(v[0]); sA[(nf+1)*72+k] = f2bf(v[1]);
        sA[(nf+2)*72+k] = f2bf(v[2]); sA[(nf+3)*72+k] = f2bf(v[3]);
      }
      long c3 = (long)(P0 + s*64 + w*16 + c)*3;
      float cp0 = center_pos[c3], cp1 = center_pos[c3+1], cp2 = center_pos[c3+2];
      __syncthreads();

      bf8v ah[2];
      #pragma unroll
      for (int ks = 0; ks < 2; ks++){
        union { bf8v v; u16 sv[8]; } ua;
        #pragma unroll
        for (int j = 0; j < 8; j++){
          int h = ks*32 + q*8 + j;
          float hv = cp0*sMisc[h] + cp1*sMisc[64+h] + cp2*sMisc[128+h] + sMisc[192+h];
          ua.sv[j] = f2bf(fmaxf(hv, 0.f));
        }
        ah[ks] = ua.v;
      }
      bf8v acf0 = *(const bf8v*)&sA[(w*16+c)*72 + q*8];
      bf8v acf1 = *(const bf8v*)&sA[(w*16+c)*72 + 32 + q*8];

      float ci = (c < 8) ? sCi[c] : 0.f;
      f32x4 aq = {ci, ci, ci, ci};
      {
        bf8v b0 = *(const bf8v*)&sWT[c*136 + q*8];
        bf8v b1 = *(const bf8v*)&sWT[c*136 + 32 + q*8];
        bf8v b2 = *(const bf8v*)&sWT[c*136 + 64 + q*8];
        bf8v b3 = *(const bf8v*)&sWT[c*136 + 96 + q*8];
        aq = __builtin_amdgcn_mfma_f32_16x16x32_bf16(ah[0], b0, aq, 0,0,0);
        aq = __builtin_amdgcn_mfma_f32_16x16x32_bf16(ah[1], b1, aq, 0,0,0);
        aq = __builtin_amdgcn_mfma_f32_16x16x32_bf16(acf0,  b2, aq, 0,0,0);
        aq = __builtin_amdgcn_mfma_f32_16x16x32_bf16(acf1,  b3, aq, 0,0,0);
      }
      __syncthreads();
      if (c < 8){
        #pragma unroll
        for (int r = 0; r < 4; r++) sQ[(w*16 + q*4 + r)*8 + c] = aq[r];
      }
      __syncthreads();
      for (int e = tid; e < 512; e += 256)
        qw[(long)(P0 + s*64)*8 + e] = sQ[e];
      __syncthreads();
    }
  }
}

// ---------------------------------------------------------------------------
// attn_kernel: 1 point/wave/iter, 8 iters.  VALU-lean:
//  - H1 in packed f16 (pk_fma/pk_max) with register coefficients -> f16 A-frag
//  - PR/logits via mfma_f32_16x16x32_f16; K path stays bf16
//  - softmax weights f32 in LDS (b128), P/V read them back (no bpermute)
//  - pos4/cp4 16-B records; scalar streams via base+immediate offsets
// ---------------------------------------------------------------------------
__global__ __launch_bounds__(256) void attn_kernel(
    const float* __restrict__ cp4, const float* __restrict__ pos4,
    const int* __restrict__ idx,
    const float* __restrict__ pe_w1, const float* __restrict__ pe_s, const float* __restrict__ pe_b,
    const float* __restrict__ pe_w2, const float* __restrict__ pe_b2,
    const float* __restrict__ we_w1, const float* __restrict__ we_s, const float* __restrict__ we_b,
    const float* __restrict__ we_w2, const float* __restrict__ we_b2,
    const u16* __restrict__ xk, const u16* __restrict__ xv, const float* __restrict__ qw,
    float* __restrict__ out)
{
  int tid = threadIdx.x;
  __shared__ float s_w1f[192], s_pb[64], s_pb2[64], s_ww2[64];
  __shared__ float s_ws8[8], s_wb8[8], s_wb28[8];
  __shared__ f32x4 s_dyn4[1312];   // union: stage 11520 B / per-wave 4*5248 B
  __shared__ float s_tile[32*66];

  char* dynb = (char*)s_dyn4;

  if (tid < 64){
    float sc = pe_s[tid];
    s_w1f[tid]     = pe_w1[tid]*sc;
    s_w1f[64+tid]  = pe_w1[64+tid]*sc;
    s_w1f[128+tid] = pe_w1[128+tid]*sc;
    s_pb[tid]  = pe_b[tid];
    s_pb2[tid] = pe_b2[tid];
    s_ww2[tid] = we_w2[tid];
  }
  if (tid >= 64 && tid < 72){
    int g = tid-64;
    s_ws8[g]=we_s[g]; s_wb8[g]=we_b[g]; s_wb28[g]=we_b2[g];
  }
  // stage pe_w2^T [col o][k] stride 72, f16
  u16* stg = (u16*)dynb;
  #pragma unroll
  for (int pp = 0; pp < 4; pp++){
    int row = pp*16 + (tid >> 4);
    int colf = (tid & 15)*4;
    f32x4 v = *(const f32x4*)&pe_w2[row*64 + colf];
    stg[(colf+0)*72+row] = f2h(v[0]); stg[(colf+1)*72+row] = f2h(v[1]);
    stg[(colf+2)*72+row] = f2h(v[2]); stg[(colf+3)*72+row] = f2h(v[3]);
  }
  // stage we_w1^T rows 0..7 (bf16), zero rows 8..15
  u16* stg2 = (u16*)(dynb + 9216);
  for (int e = tid; e < 512; e += 256){
    int k = e >> 3, cc = e & 7;
    stg2[cc*72 + k] = f2bf(we_w1[e]);
  }
  for (int e = tid; e < 576; e += 256) stg2[576 + e] = 0;
  __syncthreads();

  int w = tid >> 6, l = tid & 63, c = l & 15, q = l >> 4, c8 = c & 7, qb = l & 48;

  f16x8 pw2f[4][2];
  bf8v ww1f[2];
  f16x8 w2B, hz8;
  #pragma unroll
  for (int t = 0; t < 4; t++){
    pw2f[t][0] = *(const f16x8*)&stg[(t*16+c)*72 + q*8];
    pw2f[t][1] = *(const f16x8*)&stg[(t*16+c)*72 + 32 + q*8];
  }
  ww1f[0] = *(const bf8v*)&stg2[c*72 + q*8];
  ww1f[1] = *(const bf8v*)&stg2[c*72 + 32 + q*8];
  {
    union { f16x8 v; u16 s[8]; } uu;
    #pragma unroll
    for (int j = 0; j < 8; j++)
      uu.s[j] = (q == 0 && c < 8) ? f2h(s_ww2[j*8 + c]) : (u16)0;
    w2B = uu.v;
    #pragma unroll
    for (int j = 0; j < 8; j++) uu.s[j] = 0;
    hz8 = uu.v;
  }
  // register-resident packed-f16 H1 coefficients (16 o-values per lane)
  h2v cw0[2][4], cw1[2][4], cw2[2][4], cb[2][4];
  #pragma unroll
  for (int ks = 0; ks < 2; ks++)
    #pragma unroll
    for (int jj = 0; jj < 4; jj++){
      int o = ks*32 + q*8 + jj*2;
      cw0[ks][jj] = mkh2(s_w1f[o],     s_w1f[o+1]);
      cw1[ks][jj] = mkh2(s_w1f[64+o],  s_w1f[65+o]);
      cw2[ks][jj] = mkh2(s_w1f[128+o], s_w1f[129+o]);
      cb [ks][jj] = mkh2(s_pb[o],      s_pb[o+1]);
    }
  float ws_c = s_ws8[c8], wb_c = s_wb8[c8], wb2_c = s_wb28[c8];
  float pb2l = s_pb2[l];
  h2v hz2 = {(_Float16)0.f, (_Float16)0.f};
  __syncthreads();   // stage region -> per-wave tiles

  // per-wave tile pointers: sv f32 16x68 (4352) | swt f32 8x20 (640) | sh f16 16x8 (256)
  float* sv  = (float*)(dynb + w*5248);
  float* swt = (float*)(dynb + w*5248 + 4352);
  u16*  sh   = (u16*) (dynb + w*5248 + 4992);

  int pbase = blockIdx.x * 32;
  int b = pbase >> 14;
  const u16* xkb = xk + (long)b * N_ * 64;
  const u16* xvb = xv + (long)b * N_ * 64;
  const f32x4* pos4b = ((const f32x4*)pos4) + (long)b * N_;
  int ch = c >> 3;
  int gl = l >> 3;

  // scalar streams: base + immediate offsets
  int pb0 = pbase + w*8;
  const int*   idxl = idx + (long)pb0*16 + c;
  const float* qwl  = qw  + (long)pb0*8 + c8;
  const f32x4* cp4l = ((const f32x4*)cp4) + pb0;

  // prefetch i=0
  int iv = idxl[0];
  float qpv = qwl[0];
  f32x4 cpv = cp4l[0];
  f32x4 ppv = pos4b[iv];
  const u16* kr0 = xkb + (size_t)iv*64;
  bf8v ka0 = *(const bf8v*)(kr0 + q*8);
  bf8v ka1 = *(const bf8v*)(kr0 + 32 + q*8);
  const u16* vr0 = xvb + (size_t)iv*64;
  uint4v va0 = *(const uint4v*)(vr0 + q*8);
  uint4v va1 = *(const uint4v*)(vr0 + 32 + q*8);

  #pragma unroll 1
  for (int i = 0; i < 8; i++){
    // ---- prefetch i+1 ----
    int ni = (i < 7) ? i+1 : i;
    int iv_n = idxl[ni*16];
    float qpv_n = qwl[ni*8];
    f32x4 cpn = cp4l[ni];
    f32x4 ppn = pos4b[iv_n];
    const u16* krn = xkb + (size_t)iv_n*64;
    bf8v kan0 = *(const bf8v*)(krn + q*8);
    bf8v kan1 = *(const bf8v*)(krn + 32 + q*8);
    const u16* vrn = xvb + (size_t)iv_n*64;
    uint4v van0 = *(const uint4v*)(vrn + q*8);
    uint4v van1 = *(const uint4v*)(vrn + 32 + q*8);

    // ---- V f32 tile: row k=c, cols q*8.. / 32+q*8.. ----
    {
      f32x4 f0, f1, f2, f3;
      #pragma unroll
      for (int jj = 0; jj < 2; jj++){
        unsigned u0 = va0[jj*2], u1 = va0[jj*2+1];
        f0[jj*2]   = bf2f((u16)u0); f0[jj*2+1] = bf2f((u16)(u0>>16));
        f1[jj*2]   = bf2f((u16)u1); f1[jj*2+1] = bf2f((u16)(u1>>16));
      }
      // note: f0 holds elems 0..1 of u0 and 0..1 of u1 interleaved wrongly if
      // built as above; build explicitly instead:
      unsigned a0 = va0[0], a1 = va0[1], a2 = va0[2], a3 = va0[3];
      f32x4 lo0 = {bf2f((u16)a0), bf2f((u16)(a0>>16)), bf2f((u16)a1), bf2f((u16)(a1>>16))};
      f32x4 hi0 = {bf2f((u16)a2), bf2f((u16)(a2>>16)), bf2f((u16)a3), bf2f((u16)(a3>>16))};
      unsigned b0 = va1[0], b1 = va1[1], b2 = va1[2], b3 = va1[3];
      f32x4 lo1 = {bf2f((u16)b0), bf2f((u16)(b0>>16)), bf2f((u16)b1), bf2f((u16)(b1>>16))};
      f32x4 hi1 = {bf2f((u16)b2), bf2f((u16)(b2>>16)), bf2f((u16)b3), bf2f((u16)(b3>>16))};
      f32x4* d0 = (f32x4*)&sv[c*68 + q*8];
      d0[0] = lo0; d0[1] = hi0;
      f32x4* d1 = (f32x4*)&sv[c*68 + 32 + q*8];
      d1[0] = lo1; d1[1] = hi1;
    }

    // ---- H1 packed f16 -> f16 A-frags ----
    float np0 = ppv[0] - cpv[0], np1 = ppv[1] - cpv[1], np2 = ppv[2] - cpv[2];
    h2v np0h = {(_Float16)np0, (_Float16)np0};
    h2v np1h = {(_Float16)np1, (_Float16)np1};
    h2v np2h = {(_Float16)np2, (_Float16)np2};
    f16x8 h1f[2];
    #pragma unroll
    for (int ks = 0; ks < 2; ks++){
      union { f16x8 v; h2v p[4]; } hu;
      #pragma unroll
      for (int jj = 0; jj < 4; jj++){
        h2v a = cb[ks][jj];
        a = np0h*cw0[ks][jj] + a;
        a = np1h*cw1[ks][jj] + a;
        a = np2h*cw2[ks][jj] + a;
        hu.p[jj] = __builtin_elementwise_max(a, hz2);
      }
      h1f[ks] = hu.v;
    }

    // ---- weight-MLP hidden (bf16 K path) ----
    f32x4 h2a = {qpv, qpv, qpv, qpv};
    h2a = __builtin_amdgcn_mfma_f32_16x16x32_bf16(ka0, ww1f[0], h2a, 0,0,0);
    h2a = __builtin_amdgcn_mfma_f32_16x16x32_bf16(ka1, ww1f[1], h2a, 0,0,0);

    // hidden relu -> sh (f16), rows k, cols g=c<8
    if (c < 8){
      #pragma unroll
      for (int r = 0; r < 4; r++)
        sh[(q*4+r)*8 + c] = f2h(fmaxf(h2a[r]*ws_c + wb_c, 0.f));
    }
    f16x8 hrow = *(const f16x8*)&sh[c*8];
    f16x8 ahf = (q == 0) ? hrow : hz8;

    // logits via f16 MFMA: wl[r] = logit[k=q*4+r][g=c]
    f32x4 wlv = {wb2_c, wb2_c, wb2_c, wb2_c};
    wlv = __builtin_amdgcn_mfma_f32_16x16x32_f16(ahf, w2B, wlv, 0,0,0);

    // softmax over 16 neighbors (logits O(1), no max-sub)
    float e0 = exp2f(wlv[0]*1.44269504f);
    float e1 = exp2f(wlv[1]*1.44269504f);
    float e2 = exp2f(wlv[2]*1.44269504f);
    float e3 = exp2f(wlv[3]*1.44269504f);
    float sm = e0+e1+e2+e3;
    sm += __shfl_xor(sm, 16, 64);
    sm += __shfl_xor(sm, 32, 64);
    float rn = 1.0f / sm;
    // weights to LDS f32: swt[g=c][k=q*4..q*4+3]
    if (c < 8){
      f32x4 ev = {e0*rn, e1*rn, e2*rn, e3*rn};
      *(f32x4*)&swt[c*20 + q*4] = ev;
    }

    // ---- P part: f16 MFMA, weights from swt, cross-quad reduce ----
    float ov[4];
    #pragma unroll
    for (int t = 0; t < 4; t++){
      f32x4 z = {0.f,0.f,0.f,0.f};
      z = __builtin_amdgcn_mfma_f32_16x16x32_f16(h1f[0], pw2f[t][0], z, 0,0,0);
      z = __builtin_amdgcn_mfma_f32_16x16x32_f16(h1f[1], pw2f[t][1], z, 0,0,0);
      f32x4 wv = *(const f32x4*)&swt[(t*2+ch)*20 + q*4];
      ov[t] = z[0]*wv[0] + z[1]*wv[1] + z[2]*wv[2] + z[3]*wv[3];
    }
    #pragma unroll
    for (int t = 0; t < 4; t++){
      ov[t] += __shfl_xor(ov[t], 16, 64);
      ov[t] += __shfl_xor(ov[t], 32, 64);
    }
    float ovsel = ov[0];
    ovsel = (q==1) ? ov[1] : ovsel;
    ovsel = (q==2) ? ov[2] : ovsel;
    ovsel = (q==3) ? ov[3] : ovsel;

    // ---- V part: per-lane output o=l, 16-tap dot ----
    float vacc = 0.f;
    {
      const f32x4* wr4 = (const f32x4*)&swt[gl*20];
      const float* svl = &sv[l];
      #pragma unroll
      for (int k4 = 0; k4 < 4; k4++){
        f32x4 wv = wr4[k4];
        vacc += svl[(4*k4+0)*68]*wv[0];
        vacc += svl[(4*k4+1)*68]*wv[1];
        vacc += svl[(4*k4+2)*68]*wv[2];
        vacc += svl[(4*k4+3)*68]*wv[3];
      }
    }

    s_tile[(w*8+i)*66 + l] = ovsel + vacc + pb2l;

    // rotate
    iv = iv_n; qpv = qpv_n; cpv = cpn; ppv = ppn;
    ka0 = kan0; ka1 = kan1; va0 = van0; va1 = van1;
  }
  __syncthreads();

  // coalesced transposed store: out[b][o][m0+pt]
  int o0 = tid >> 5, pt = tid & 31;
  int m0 = pbase & (M_-1);
  long outb = ((long)b*64) * M_ + m0 + pt;
  #pragma unroll
  for (int ii = 0; ii < 8; ii++){
    int o = o0*8 + ii;
    out[outb + (long)o*M_] = s_tile[pt*66 + o];
  }
}

extern "C" void kernel_launch(void* const* d_in, const int* in_sizes, int n_in,
                              void* d_out, int out_size, void* d_ws, size_t ws_size,
                              hipStream_t stream) {
  const float* center_pos = (const float*)d_in[0];
  const float* center_fea = (const float*)d_in[1];
  const float* pos        = (const float*)d_in[2];
  const float* fea        = (const float*)d_in[3];
  const int*   idx        = (const int*)d_in[4];
  const float* Wq = (const float*)d_in[5];   const float* bq = (const float*)d_in[6];
  const float* Wk = (const float*)d_in[7];   const float* bk = (const float*)d_in[8];
  const float* Wv = (const float*)d_in[9];   const float* bv = (const float*)d_in[10];
  const float* cpe_w1 = (const float*)d_in[11]; const float* cpe_s = (const float*)d_in[12];
  const float* cpe_b  = (const float*)d_in[13]; const float* cpe_w2 = (const float*)d_in[14];
  const float* cpe_b2 = (const float*)d_in[15];
  const float* pe_w1 = (const float*)d_in[16]; const float* pe_s = (const float*)d_in[17];
  const float* pe_b  = (const float*)d_in[18]; const float* pe_w2 = (const float*)d_in[19];
  const float* pe_b2 = (const float*)d_in[20];
  const float* we_w1 = (const float*)d_in[21]; const float* we_s = (const float*)d_in[22];
  const float* we_b  = (const float*)d_in[23]; const float* we_w2 = (const float*)d_in[24];
  const float* we_b2 = (const float*)d_in[25];

  // ws: xk u16 | xv u16 | qw f32 | pos4 f32x4 | cp4 f32x4
  const size_t SZ = (size_t)B_*N_*64;
  u16* xk = (u16*)d_ws;
  u16* xv = xk + SZ;
  float* qwp = (float*)(xv + SZ);
  float* pos4p = qwp + (size_t)B_*M_*8;
  float* cp4p  = pos4p + (size_t)B_*N_*4;
  float* outp = (float*)d_out;

  hipLaunchKernelGGL(pre_kernel, dim3(512), dim3(256), 0, stream,
      center_pos, center_fea, pos, fea, Wq, bq, Wk, bk, Wv, bv,
      cpe_w1, cpe_s, cpe_b, cpe_w2, cpe_b2, we_w1,
      xk, xv, qwp, pos4p, cp4p);
  hipLaunchKernelGGL(attn_kernel, dim3(2048), dim3(256), 0, stream,
      cp4p, pos4p, idx, pe_w1, pe_s, pe_b, pe_w2, pe_b2,
      we_w1, we_s, we_b, we_w2, we_b2, xk, xv, qwp, outp);
}